// Round 14
// baseline (111.489 us; speedup 1.0000x reference)
//
#include <hip/hip_runtime.h>

// ConvCRF forward, MI355X — round 14: uniform iterations + flat distributed
// barrier + 3 syncs/iter.
// R13 post-mortem: crf 53.5us; pipes ~26% busy (latency-bound). Residual per
// iter: barrier release round-trip via block0, 4 syncthreads, staging latency;
// plus iter0's full-halo softmax staging from u (~120 scalar loads/thread).
// Changes:
//  - initial sm0 published from REGISTERS (smx0 of own unaries, already loaded)
//    -> iter0 staging becomes a normal ring-stage; all 5 iterations uniform
//    (5 barriers, each cheap).
//  - flat barrier: every block's tid0 spin-sums the 8 cache-line-spread
//    counters (no release word, no block0 round-trip). Plain loads don't
//    serialize like RMWs.
//  - publish at loop top (drained by barrier-entry __syncthreads); smH interior
//    self-write folded into the staging phase -> 3 syncs/iter (entry, exit,
//    post-staging).
// Proven pieces: 200-block grid, relaxed agent-atomic gsm exchange (IF$-coherent,
// no cache-maintenance fences), f16 ping-pong sm0, batch algebra sm1=1-sm0,
// diag fast path, LDS tap weights, O(19)/entry M prologue, distributed counters.

typedef __attribute__((ext_vector_type(4))) _Float16 half4;
typedef __attribute__((ext_vector_type(2))) _Float16 half2f;
typedef __attribute__((ext_vector_type(4))) float float4v;

#define HH 160
#define WW 160
#define NPIX (HH*WW)
#define NC 19
#define NG 5
#define SPAN 3
#define TR 8
#define TC 16
#define NPXT 128
#define LR 14              // TR + 2*SPAN
#define LC 22              // TC + 2*SPAN
#define LCP 24             // padded halo row stride (half4 units)
#define HSTRIDE (LR*LCP)   // 336
#define NHALO (LR*LC)      // 308
#define NRING 180          // NHALO - 8*16 interior
#define NBLK 200
#define NTHR 640
#define EPSF 1e-20f
#define MAGICV 0x5EEDF00Du

// bar layout (u32 words): [0]=magic; counters at words 32,64,...,256 (128B apart)
#define BAR_CNT(k) (32 + (k)*32)

#define SZ_A    30720
#define OFF_WB  SZ_A
#define SHM_SZ  (SZ_A + 25*128*8)   // 56,320

__device__ __forceinline__ float fast_rcp(float x) { return __builtin_amdgcn_rcpf(x); }

__device__ __forceinline__ float smx0(float q0, float q1) {
    const float m  = fmaxf(q0, q1);
    const float e0 = __expf(q0 - m);
    const float e1 = __expf(q1 - m);
    return e0 * fast_rcp(e0 + e1);
}

__global__ void __launch_bounds__(NTHR) crf_kernel(
        const float* __restrict__ u,
        const float* __restrict__ rgb,
        const float* __restrict__ sw,
        const float* __restrict__ bw,
        const float* __restrict__ compat,
        unsigned long long* __restrict__ gsmA,   // ping-pong sm0 fields
        unsigned long long* __restrict__ gsmB,
        unsigned* __restrict__ bar,
        float* __restrict__ out) {
    __shared__ __align__(16) char shm[SHM_SZ];
    __shared__ float Msh[960];                   // 20x48 rows [Ms|Mb|RS|pad]
    __shared__ float rowsum[NC];
    __shared__ int   diagflag;
    float4*   rgbL = (float4*)shm;               // prologue only
    half4*    smH  = (half4*)shm;                // per-iter sm0 halo (f16)
    float*    accF = (float*)shm;                // general-path epilogue
    unsigned* wbW  = (unsigned*)(shm + OFF_WB);
    const uint2* wbP = (const uint2*)(shm + OFF_WB);

    constexpr float WSPC[49] = {
        0.36787944f,0.48567179f,0.57375342f,0.60653066f,0.57375342f,0.48567179f,0.36787944f,
        0.48567179f,0.64118039f,0.75746513f,0.80073740f,0.75746513f,0.64118039f,0.48567179f,
        0.57375342f,0.75746513f,0.89483932f,0.94595947f,0.89483932f,0.75746513f,0.57375342f,
        0.60653066f,0.80073740f,0.94595947f,1.00000000f,0.94595947f,0.80073740f,0.60653066f,
        0.57375342f,0.75746513f,0.89483932f,0.94595947f,0.89483932f,0.75746513f,0.57375342f,
        0.48567179f,0.64118039f,0.75746513f,0.80073740f,0.75746513f,0.64118039f,0.48567179f,
        0.36787944f,0.48567179f,0.57375342f,0.60653066f,0.57375342f,0.48567179f,0.36787944f };

    const int tid = threadIdx.x;
    const int px  = tid & 127;
    const int g   = tid >> 7;
    const int r   = px >> 4, c = px & 15;
    const int ti0 = blockIdx.y * TR, tj0 = blockIdx.x * TC;
    const int gp  = (ti0 + r) * WW + (tj0 + c);
    const int ctr = (r + SPAN) * LCP + (c + SPAN);
    const int ku  = 4 * g;
    const int bid = blockIdx.y * 10 + blockIdx.x;    // 0..199

    // ---- barrier init handshake (ws poisoned 0xAA before every launch) ----
    if (bid == 0 && tid == 0) {
        #pragma unroll
        for (int k = 0; k < 8; ++k)
            __hip_atomic_store(&bar[BAR_CNT(k)], 0u, __ATOMIC_RELAXED, __HIP_MEMORY_SCOPE_AGENT);
        __hip_atomic_store(&bar[0], MAGICV, __ATOMIC_RELEASE, __HIP_MEMORY_SCOPE_AGENT);
    }
    if (tid == 0) {
        diagflag = 1;
        while (__hip_atomic_load(&bar[0], __ATOMIC_ACQUIRE, __HIP_MEMORY_SCOPE_AGENT) != MAGICV)
            __builtin_amdgcn_s_sleep(2);
    }
    if (tid < NC) {
        float rs = 0.0f;
        for (int cb = 0; cb < NC; ++cb) rs += sw[tid*NC + cb] + bw[tid*NC + cb];
        rowsum[tid] = rs;
    }
    __syncthreads();

    // ---- phase 0: M = [compat@sw | compat@bw | RS] into LDS, O(19)/entry ----
    for (int e = tid; e < 960; e += NTHR) {
        const int k = e / 48, cc2 = e % 48;
        float acc = 0.0f;
        if (k < NC) {
            if (cc2 < NC) {
                for (int j = 0; j < NC; ++j) acc += compat[k*NC + j] * sw[j*NC + cc2];
            } else if (cc2 >= 20 && cc2 < 20 + NC) {
                const int cb = cc2 - 20;
                for (int j = 0; j < NC; ++j) acc += compat[k*NC + j] * bw[j*NC + cb];
            } else if (cc2 == 40) {
                for (int j = 0; j < NC; ++j) acc += compat[k*NC + j] * rowsum[j];
            }
        }
        Msh[e] = acc;
        bool off = false;
        if (k < NC) {
            if (cc2 < NC && cc2 != k && acc != 0.0f) off = true;
            if (cc2 >= 20 && cc2 < 20 + NC && (cc2 - 20) != k && acc != 0.0f) off = true;
        }
        if (off) atomicAnd(&diagflag, 0);
    }
    __syncthreads();

    float dsv[4], dbv[4];
    #pragma unroll
    for (int i = 0; i < 4; ++i) {
        dsv[i] = Msh[(ku + i) * 48 + (ku + i)];
        dbv[i] = Msh[(ku + i) * 48 + 20 + (ku + i)];
    }
    const bool isdiag = (diagflag != 0);

    // ---- phase 1: rgb halo, both batches ----
    for (int e = tid; e < 2 * NHALO; e += NTHR) {
        const int bb = e / NHALO, pos = e % NHALO;
        const int hr = pos / LC, hc = pos % LC;
        const int yi = ti0 - SPAN + hr, xj = tj0 - SPAN + hc;
        float4 rv = make_float4(0.f, 0.f, 0.f, 0.f);
        if ((unsigned)yi < HH && (unsigned)xj < WW) {
            const float* p = rgb + ((size_t)(bb * NPIX) + yi * WW + xj) * 3;
            rv = make_float4(p[0]*(1.f/160.f), p[1]*(1.f/160.f), p[2]*(1.f/160.f), 1.f);
        }
        rgbL[(bb ? HSTRIDE : 0) + hr * LCP + hc] = rv;
    }
    __syncthreads();

    // ---- phase 2a: bilateral weights (tap-subset per group) -> LDS pairs ----
    {
        const float4 cv0 = rgbL[ctr];
        const float4 cv1 = rgbL[HSTRIDE + ctr];
        const int tapb = g * 10;
        const int ntap = (g == 4) ? 9 : 10;
        for (int i = 0; i < ntap; ++i) {
            const int t = tapb + i;
            const int dx = t / 7 - SPAN, dy = t % 7 - SPAN;
            const int n = ctr + dx * LCP + dy;
            const float4 nv0 = rgbL[n];
            const float4 nv1 = rgbL[HSTRIDE + n];
            const float wsm = __expf(-(float)(dx*dx + dy*dy) * (1.f/18.f)) * nv0.w;
            const float dr0 = cv0.x-nv0.x, dg0 = cv0.y-nv0.y, db0 = cv0.z-nv0.z;
            const float dr1 = cv1.x-nv1.x, dg1 = cv1.y-nv1.y, db1 = cv1.z-nv1.z;
            const float wb0 = wsm * __expf(-0.5f*(dr0*dr0+dg0*dg0+db0*db0));
            const float wb1 = wsm * __expf(-0.5f*(dr1*dr1+dg1*dg1+db1*db1));
            half2f hw = {(_Float16)wb0, (_Float16)wb1};
            unsigned uw; __builtin_memcpy(&uw, &hw, 4);
            wbW[(t >> 1) * 256 + px * 2 + (t & 1)] = uw;
        }
        if (g == 4) wbW[24 * 256 + px * 2 + 1] = 0u;
    }
    __syncthreads();

    // ---- phase 2b: per-pixel inverse norms ----
    float snI, bnI0, bnI1;
    {
        float sn = 0.f, bn0 = 0.f, bn1 = 0.f;
        #pragma unroll
        for (int t = 0; t < 49; ++t) {
            const unsigned uw = wbW[(t >> 1) * 256 + px * 2 + (t & 1)];
            half2f hw; __builtin_memcpy(&hw, &uw, 4);
            bn0 += (float)hw.x; bn1 += (float)hw.y;
            const int dx = t / 7 - SPAN, dy = t % 7 - SPAN;
            const int yi = ti0 + r + dx, xj = tj0 + c + dy;
            sn += (((unsigned)yi < HH) && ((unsigned)xj < WW)) ? WSPC[t] : 0.0f;
        }
        snI  = fast_rcp(sn + EPSF);
        bnI0 = fast_rcp(bn0 + EPSF);
        bnI1 = fast_rcp(bn1 + EPSF);
    }

    // ---- one-time: own unaries + initial sm0 (registers only) ----
    float uv0[4], uv1[4];
    #pragma unroll
    for (int i = 0; i < 4; ++i) {
        const int ch = 4*g + i;
        uv0[i] = (ch < NC) ? u[(size_t)gp * NC + ch] : 0.0f;
        uv1[i] = (ch < NC) ? u[((size_t)NPIX + gp) * NC + ch] : 0.0f;
    }
    half4 sh;
    #pragma unroll
    for (int i = 0; i < 4; ++i) sh[i] = (_Float16)smx0(uv0[i], uv1[i]);

    for (int it = 0; it < 5; ++it) {
        // ---- publish own sm0 for this iteration (even->A, odd->B) ----
        {
            unsigned long long u64; __builtin_memcpy(&u64, &sh, 8);
            unsigned long long* gdst = ((it & 1) ? gsmB : gsmA);
            __hip_atomic_store(&gdst[g * NPIX + gp], u64,
                               __ATOMIC_RELAXED, __HIP_MEMORY_SCOPE_AGENT);
        }
        // ---- flat distributed barrier ----
        __syncthreads();             // drains every wave's publish (vmcnt) + taps
        if (tid == 0) {
            __hip_atomic_fetch_add(&bar[BAR_CNT(bid & 7)], 1u,
                                   __ATOMIC_RELAXED, __HIP_MEMORY_SCOPE_AGENT);
            const unsigned tgt = (unsigned)(NBLK * (it + 1));
            unsigned sum;
            do {
                sum = 0;
                #pragma unroll
                for (int k = 0; k < 8; ++k)
                    sum += __hip_atomic_load(&bar[BAR_CNT(k)],
                                             __ATOMIC_RELAXED, __HIP_MEMORY_SCOPE_AGENT);
                if (sum < tgt) __builtin_amdgcn_s_sleep(2);
            } while (sum < tgt);
        }
        __syncthreads();

        // ---- stage: ring from gsm + interior self-write from registers ----
        const unsigned long long* gsrc = ((it & 1) ? gsmB : gsmA);
        smH[g * HSTRIDE + ctr] = sh;
        #pragma unroll
        for (int k2 = 0; k2 < 2; ++k2) {
            const int e = tid + NTHR * k2;
            if (e < NG * NRING) {
                const int sg = e / NRING, re = e - sg * NRING;
                int hr, hc;
                if (re < 66)        { hr = re / 22;          hc = re % 22; }
                else if (re < 132)  { const int t2 = re - 66;  hr = 11 + t2 / 22; hc = t2 % 22; }
                else                { const int t2 = re - 132; hr = 3 + t2 / 6;
                                      const int s = t2 % 6;    hc = (s < 3) ? s : s + 16; }
                const int yi = ti0 - SPAN + hr, xj = tj0 - SPAN + hc;
                half4 hv = (half4)(_Float16)0.0f;
                if ((unsigned)yi < HH && (unsigned)xj < WW) {
                    const unsigned long long raw =
                        __hip_atomic_load(&gsrc[sg * NPIX + yi * WW + xj],
                                          __ATOMIC_RELAXED, __HIP_MEMORY_SCOPE_AGENT);
                    __builtin_memcpy(&hv, &raw, 8);
                }
                smH[sg * HSTRIDE + hr * LCP + hc] = hv;
            }
        }
        __syncthreads();

        // ---- 49 taps as 24 pairs + 1 ----
        float4v sAv = (float4v)0.0f, b0a = (float4v)0.0f, b1a = (float4v)0.0f;
        const half4* pl = smH + g * HSTRIDE;
        #pragma unroll
        for (int i = 0; i < 24; ++i) {
            const uint2 wp = wbP[i * 128 + px];
            #pragma unroll
            for (int s = 0; s < 2; ++s) {
                const int t = 2*i + s;
                const int dx = t / 7 - SPAN, dy = t % 7 - SPAN;
                half2f hw; __builtin_memcpy(&hw, s ? &wp.y : &wp.x, 4);
                const float w0 = (float)hw.x, w1 = (float)hw.y;
                const half4 v = pl[ctr + dx*LCP + dy];
                const float4v f = {(float)v[0], (float)v[1], (float)v[2], (float)v[3]};
                sAv += WSPC[t] * f;
                b0a += w0 * f;
                b1a += w1 * f;
            }
        }
        {   // tap 48
            const uint2 wp = wbP[24 * 128 + px];
            half2f hw; __builtin_memcpy(&hw, &wp.x, 4);
            const float w0 = (float)hw.x, w1 = (float)hw.y;
            const half4 v = pl[ctr + SPAN*LCP + SPAN];
            const float4v f = {(float)v[0], (float)v[1], (float)v[2], (float)v[3]};
            sAv += WSPC[48] * f;
            b0a += w0 * f;
            b1a += w1 * f;
        }

        float q0v[4], q1v[4];
        if (isdiag) {
            #pragma unroll
            for (int i = 0; i < 4; ++i) {
                const float sAn = sAv[i] * snI;
                const float b0n = b0a[i] * bnI0;
                const float b1x = b1a[i] * bnI1;
                q0v[i] = uv0[i] - dsv[i]*sAn - dbv[i]*b0n;
                q1v[i] = uv1[i] - (dsv[i] + dbv[i]) + dsv[i]*sAn + dbv[i]*b1x;
            }
        } else {
            __syncthreads();   // smH dead -> region A becomes accF
            #pragma unroll
            for (int i = 0; i < 4; ++i) {
                accF[(4*g + i) * NPXT + px]      = sAv[i] * snI;
                accF[(20 + 4*g + i) * NPXT + px] = b0a[i] * bnI0;
                accF[(40 + 4*g + i) * NPXT + px] = b1a[i] * bnI1;
            }
            __syncthreads();
            float t1[4] = {0,0,0,0}, t2[4] = {0,0,0,0}, t3[4] = {0,0,0,0};
            #pragma unroll
            for (int cc = 0; cc < 20; ++cc) {
                const float sv  = accF[cc * NPXT + px];
                const float b0v = accF[(20 + cc) * NPXT + px];
                const float b1v = accF[(40 + cc) * NPXT + px];
                #pragma unroll
                for (int i = 0; i < 4; ++i) {
                    const float* mk = Msh + (ku + i) * 48;
                    t1[i] += mk[cc] * sv;
                    t2[i] += mk[20 + cc] * b0v;
                    t3[i] += mk[20 + cc] * b1v;
                }
            }
            #pragma unroll
            for (int i = 0; i < 4; ++i) {
                const float rs = Msh[(ku + i) * 48 + 40];
                q0v[i] = uv0[i] - t1[i] - t2[i];
                q1v[i] = uv1[i] - rs + t1[i] + t3[i];
            }
        }

        if (it == 4) {
            #pragma unroll
            for (int i = 0; i < 4; ++i) {
                const int ch = 4*g + i;
                if (ch < NC) {
                    out[(size_t)gp * NC + ch]          = q0v[i];
                    out[((size_t)NPIX + gp) * NC + ch] = q1v[i];
                }
            }
        } else {
            #pragma unroll
            for (int i = 0; i < 4; ++i) sh[i] = (_Float16)smx0(q0v[i], q1v[i]);
        }
    }
}

extern "C" void kernel_launch(void* const* d_in, const int* in_sizes, int n_in,
                              void* d_out, int out_size, void* d_ws, size_t ws_size,
                              hipStream_t stream) {
    const float* u      = (const float*)d_in[0];
    const float* rgb    = (const float*)d_in[1];
    const float* sw     = (const float*)d_in[2];
    const float* bw     = (const float*)d_in[3];
    const float* compat = (const float*)d_in[4];
    float* out = (float*)d_out;

    unsigned long long* gsmA = (unsigned long long*)d_ws;              // 1,024,000 B
    unsigned long long* gsmB = (unsigned long long*)((char*)d_ws + 1024000);
    unsigned* bar = (unsigned*)((char*)d_ws + 2048000);                // ~1.2 KB used

    crf_kernel<<<dim3(WW/TC, HH/TR, 1), dim3(NTHR), 0, stream>>>(
        u, rgb, sw, bw, compat, gsmA, gsmB, bar, out);
}

// Round 15
// 108.448 us; speedup vs baseline: 1.0280x; 1.0280x over previous
//
#include <hip/hip_runtime.h>

// ConvCRF forward, MI355X — round 15: neighbor-only epoch sync (no global barrier).
// R14 post-mortem: barrier calibrated at ~4us each (5 of them = ~20us of 53).
// Global convergence is overkill: staging reads only the 8 spatial neighbors'
// sm (halo 3 < tile 8x16). Replace barrier with per-block epochs:
//  - publish sm -> __syncthreads (vmcnt(0) drains all waves' publishes to IF$)
//    -> tid0 stores epoch[bid]=it+1 (relaxed, own 128B-strided word, no RMW)
//    -> tid0 polls 8 neighbor epochs >= it+1 -> __syncthreads.
//  - safety: wait-set is a SUBSET of the proven global barrier's (no deadlock
//    risk beyond proven 200-block co-residency). Ping-pong buffers protect the
//    max skew: N can overwrite buffer(it) only after B published it+1, which
//    happens after B finished reading buffer(it).
// Everything else byte-identical to R14 (uniform iterations, register publish,
// ring staging + interior self-write, diag fast path, LDS tap weights,
// O(19)/entry M prologue, relaxed agent-atomic f16 sm exchange).

typedef __attribute__((ext_vector_type(4))) _Float16 half4;
typedef __attribute__((ext_vector_type(2))) _Float16 half2f;
typedef __attribute__((ext_vector_type(4))) float float4v;

#define HH 160
#define WW 160
#define NPIX (HH*WW)
#define NC 19
#define NG 5
#define SPAN 3
#define TR 8
#define TC 16
#define NPXT 128
#define LR 14              // TR + 2*SPAN
#define LC 22              // TC + 2*SPAN
#define LCP 24             // padded halo row stride (half4 units)
#define HSTRIDE (LR*LCP)   // 336
#define NHALO (LR*LC)      // 308
#define NRING 180          // NHALO - 8*16 interior
#define NBLK 200
#define NTHR 640
#define EPSF 1e-20f
#define MAGICV 0x5EEDF00Du

// bar layout (u32 words): [0]=magic; epoch[b] at word 32+b*32 (128B stride)
#define EPW(b) (32 + (b)*32)

#define SZ_A    30720
#define OFF_WB  SZ_A
#define SHM_SZ  (SZ_A + 25*128*8)   // 56,320

__device__ __forceinline__ float fast_rcp(float x) { return __builtin_amdgcn_rcpf(x); }

__device__ __forceinline__ float smx0(float q0, float q1) {
    const float m  = fmaxf(q0, q1);
    const float e0 = __expf(q0 - m);
    const float e1 = __expf(q1 - m);
    return e0 * fast_rcp(e0 + e1);
}

__global__ void __launch_bounds__(NTHR) crf_kernel(
        const float* __restrict__ u,
        const float* __restrict__ rgb,
        const float* __restrict__ sw,
        const float* __restrict__ bw,
        const float* __restrict__ compat,
        unsigned long long* __restrict__ gsmA,   // ping-pong sm0 fields
        unsigned long long* __restrict__ gsmB,
        unsigned* __restrict__ bar,
        float* __restrict__ out) {
    __shared__ __align__(16) char shm[SHM_SZ];
    __shared__ float Msh[960];                   // 20x48 rows [Ms|Mb|RS|pad]
    __shared__ float rowsum[NC];
    __shared__ int   diagflag;
    float4*   rgbL = (float4*)shm;               // prologue only
    half4*    smH  = (half4*)shm;                // per-iter sm0 halo (f16)
    float*    accF = (float*)shm;                // general-path epilogue
    unsigned* wbW  = (unsigned*)(shm + OFF_WB);
    const uint2* wbP = (const uint2*)(shm + OFF_WB);

    constexpr float WSPC[49] = {
        0.36787944f,0.48567179f,0.57375342f,0.60653066f,0.57375342f,0.48567179f,0.36787944f,
        0.48567179f,0.64118039f,0.75746513f,0.80073740f,0.75746513f,0.64118039f,0.48567179f,
        0.57375342f,0.75746513f,0.89483932f,0.94595947f,0.89483932f,0.75746513f,0.57375342f,
        0.60653066f,0.80073740f,0.94595947f,1.00000000f,0.94595947f,0.80073740f,0.60653066f,
        0.57375342f,0.75746513f,0.89483932f,0.94595947f,0.89483932f,0.75746513f,0.57375342f,
        0.48567179f,0.64118039f,0.75746513f,0.80073740f,0.75746513f,0.64118039f,0.48567179f,
        0.36787944f,0.48567179f,0.57375342f,0.60653066f,0.57375342f,0.48567179f,0.36787944f };

    const int tid = threadIdx.x;
    const int px  = tid & 127;
    const int g   = tid >> 7;
    const int r   = px >> 4, c = px & 15;
    const int ti0 = blockIdx.y * TR, tj0 = blockIdx.x * TC;
    const int gp  = (ti0 + r) * WW + (tj0 + c);
    const int ctr = (r + SPAN) * LCP + (c + SPAN);
    const int ku  = 4 * g;
    const int bid = blockIdx.y * 10 + blockIdx.x;    // grid (10, 20)

    // neighbor epochs to wait on (pad missing neighbors with own bid)
    int nb[8];
    {
        const int bx = blockIdx.x, by = blockIdx.y;
        int k = 0;
        #pragma unroll
        for (int dy2 = -1; dy2 <= 1; ++dy2)
            #pragma unroll
            for (int dx2 = -1; dx2 <= 1; ++dx2) {
                if (dx2 == 0 && dy2 == 0) continue;
                const int nx = bx + dx2, ny = by + dy2;
                nb[k++] = ((unsigned)nx < 10u && (unsigned)ny < 20u) ? (ny*10 + nx) : bid;
            }
    }

    // ---- epoch init handshake (ws poisoned 0xAA before every launch) ----
    if (bid == 0) {
        for (int e = tid; e < NBLK; e += NTHR)
            __hip_atomic_store(&bar[EPW(e)], 0u, __ATOMIC_RELAXED, __HIP_MEMORY_SCOPE_AGENT);
        __syncthreads();      // drain zeroing stores before magic
        if (tid == 0)
            __hip_atomic_store(&bar[0], MAGICV, __ATOMIC_RELEASE, __HIP_MEMORY_SCOPE_AGENT);
    }
    if (tid == 0) {
        diagflag = 1;
        while (__hip_atomic_load(&bar[0], __ATOMIC_ACQUIRE, __HIP_MEMORY_SCOPE_AGENT) != MAGICV)
            __builtin_amdgcn_s_sleep(2);
    }
    if (tid < NC) {
        float rs = 0.0f;
        for (int cb = 0; cb < NC; ++cb) rs += sw[tid*NC + cb] + bw[tid*NC + cb];
        rowsum[tid] = rs;
    }
    __syncthreads();

    // ---- phase 0: M = [compat@sw | compat@bw | RS] into LDS, O(19)/entry ----
    for (int e = tid; e < 960; e += NTHR) {
        const int k = e / 48, cc2 = e % 48;
        float acc = 0.0f;
        if (k < NC) {
            if (cc2 < NC) {
                for (int j = 0; j < NC; ++j) acc += compat[k*NC + j] * sw[j*NC + cc2];
            } else if (cc2 >= 20 && cc2 < 20 + NC) {
                const int cb = cc2 - 20;
                for (int j = 0; j < NC; ++j) acc += compat[k*NC + j] * bw[j*NC + cb];
            } else if (cc2 == 40) {
                for (int j = 0; j < NC; ++j) acc += compat[k*NC + j] * rowsum[j];
            }
        }
        Msh[e] = acc;
        bool off = false;
        if (k < NC) {
            if (cc2 < NC && cc2 != k && acc != 0.0f) off = true;
            if (cc2 >= 20 && cc2 < 20 + NC && (cc2 - 20) != k && acc != 0.0f) off = true;
        }
        if (off) atomicAnd(&diagflag, 0);
    }
    __syncthreads();

    float dsv[4], dbv[4];
    #pragma unroll
    for (int i = 0; i < 4; ++i) {
        dsv[i] = Msh[(ku + i) * 48 + (ku + i)];
        dbv[i] = Msh[(ku + i) * 48 + 20 + (ku + i)];
    }
    const bool isdiag = (diagflag != 0);

    // ---- phase 1: rgb halo, both batches ----
    for (int e = tid; e < 2 * NHALO; e += NTHR) {
        const int bb = e / NHALO, pos = e % NHALO;
        const int hr = pos / LC, hc = pos % LC;
        const int yi = ti0 - SPAN + hr, xj = tj0 - SPAN + hc;
        float4 rv = make_float4(0.f, 0.f, 0.f, 0.f);
        if ((unsigned)yi < HH && (unsigned)xj < WW) {
            const float* p = rgb + ((size_t)(bb * NPIX) + yi * WW + xj) * 3;
            rv = make_float4(p[0]*(1.f/160.f), p[1]*(1.f/160.f), p[2]*(1.f/160.f), 1.f);
        }
        rgbL[(bb ? HSTRIDE : 0) + hr * LCP + hc] = rv;
    }
    __syncthreads();

    // ---- phase 2a: bilateral weights (tap-subset per group) -> LDS pairs ----
    {
        const float4 cv0 = rgbL[ctr];
        const float4 cv1 = rgbL[HSTRIDE + ctr];
        const int tapb = g * 10;
        const int ntap = (g == 4) ? 9 : 10;
        for (int i = 0; i < ntap; ++i) {
            const int t = tapb + i;
            const int dx = t / 7 - SPAN, dy = t % 7 - SPAN;
            const int n = ctr + dx * LCP + dy;
            const float4 nv0 = rgbL[n];
            const float4 nv1 = rgbL[HSTRIDE + n];
            const float wsm = __expf(-(float)(dx*dx + dy*dy) * (1.f/18.f)) * nv0.w;
            const float dr0 = cv0.x-nv0.x, dg0 = cv0.y-nv0.y, db0 = cv0.z-nv0.z;
            const float dr1 = cv1.x-nv1.x, dg1 = cv1.y-nv1.y, db1 = cv1.z-nv1.z;
            const float wb0 = wsm * __expf(-0.5f*(dr0*dr0+dg0*dg0+db0*db0));
            const float wb1 = wsm * __expf(-0.5f*(dr1*dr1+dg1*dg1+db1*db1));
            half2f hw = {(_Float16)wb0, (_Float16)wb1};
            unsigned uw; __builtin_memcpy(&uw, &hw, 4);
            wbW[(t >> 1) * 256 + px * 2 + (t & 1)] = uw;
        }
        if (g == 4) wbW[24 * 256 + px * 2 + 1] = 0u;
    }
    __syncthreads();

    // ---- phase 2b: per-pixel inverse norms ----
    float snI, bnI0, bnI1;
    {
        float sn = 0.f, bn0 = 0.f, bn1 = 0.f;
        #pragma unroll
        for (int t = 0; t < 49; ++t) {
            const unsigned uw = wbW[(t >> 1) * 256 + px * 2 + (t & 1)];
            half2f hw; __builtin_memcpy(&hw, &uw, 4);
            bn0 += (float)hw.x; bn1 += (float)hw.y;
            const int dx = t / 7 - SPAN, dy = t % 7 - SPAN;
            const int yi = ti0 + r + dx, xj = tj0 + c + dy;
            sn += (((unsigned)yi < HH) && ((unsigned)xj < WW)) ? WSPC[t] : 0.0f;
        }
        snI  = fast_rcp(sn + EPSF);
        bnI0 = fast_rcp(bn0 + EPSF);
        bnI1 = fast_rcp(bn1 + EPSF);
    }

    // ---- one-time: own unaries + initial sm0 (registers only) ----
    float uv0[4], uv1[4];
    #pragma unroll
    for (int i = 0; i < 4; ++i) {
        const int ch = 4*g + i;
        uv0[i] = (ch < NC) ? u[(size_t)gp * NC + ch] : 0.0f;
        uv1[i] = (ch < NC) ? u[((size_t)NPIX + gp) * NC + ch] : 0.0f;
    }
    half4 sh;
    #pragma unroll
    for (int i = 0; i < 4; ++i) sh[i] = (_Float16)smx0(uv0[i], uv1[i]);

    for (int it = 0; it < 5; ++it) {
        // ---- publish own sm0 for this iteration (even->A, odd->B) ----
        {
            unsigned long long u64; __builtin_memcpy(&u64, &sh, 8);
            unsigned long long* gdst = ((it & 1) ? gsmB : gsmA);
            __hip_atomic_store(&gdst[g * NPIX + gp], u64,
                               __ATOMIC_RELAXED, __HIP_MEMORY_SCOPE_AGENT);
        }
        // ---- neighbor-only epoch sync ----
        __syncthreads();             // vmcnt(0): all waves' publishes at IF$
        if (tid == 0) {
            __hip_atomic_store(&bar[EPW(bid)], (unsigned)(it + 1),
                               __ATOMIC_RELAXED, __HIP_MEMORY_SCOPE_AGENT);
            const unsigned tgt = (unsigned)(it + 1);
            unsigned mn;
            do {
                mn = 0xFFFFFFFFu;
                #pragma unroll
                for (int k = 0; k < 8; ++k) {
                    const unsigned e = __hip_atomic_load(&bar[EPW(nb[k])],
                                                         __ATOMIC_RELAXED, __HIP_MEMORY_SCOPE_AGENT);
                    mn = (e < mn) ? e : mn;
                }
                if (mn < tgt) __builtin_amdgcn_s_sleep(1);
            } while (mn < tgt);
        }
        __syncthreads();

        // ---- stage: ring from gsm + interior self-write from registers ----
        const unsigned long long* gsrc = ((it & 1) ? gsmB : gsmA);
        smH[g * HSTRIDE + ctr] = sh;
        #pragma unroll
        for (int k2 = 0; k2 < 2; ++k2) {
            const int e = tid + NTHR * k2;
            if (e < NG * NRING) {
                const int sg = e / NRING, re = e - sg * NRING;
                int hr, hc;
                if (re < 66)        { hr = re / 22;          hc = re % 22; }
                else if (re < 132)  { const int t2 = re - 66;  hr = 11 + t2 / 22; hc = t2 % 22; }
                else                { const int t2 = re - 132; hr = 3 + t2 / 6;
                                      const int s = t2 % 6;    hc = (s < 3) ? s : s + 16; }
                const int yi = ti0 - SPAN + hr, xj = tj0 - SPAN + hc;
                half4 hv = (half4)(_Float16)0.0f;
                if ((unsigned)yi < HH && (unsigned)xj < WW) {
                    const unsigned long long raw =
                        __hip_atomic_load(&gsrc[sg * NPIX + yi * WW + xj],
                                          __ATOMIC_RELAXED, __HIP_MEMORY_SCOPE_AGENT);
                    __builtin_memcpy(&hv, &raw, 8);
                }
                smH[sg * HSTRIDE + hr * LCP + hc] = hv;
            }
        }
        __syncthreads();

        // ---- 49 taps as 24 pairs + 1 ----
        float4v sAv = (float4v)0.0f, b0a = (float4v)0.0f, b1a = (float4v)0.0f;
        const half4* pl = smH + g * HSTRIDE;
        #pragma unroll
        for (int i = 0; i < 24; ++i) {
            const uint2 wp = wbP[i * 128 + px];
            #pragma unroll
            for (int s = 0; s < 2; ++s) {
                const int t = 2*i + s;
                const int dx = t / 7 - SPAN, dy = t % 7 - SPAN;
                half2f hw; __builtin_memcpy(&hw, s ? &wp.y : &wp.x, 4);
                const float w0 = (float)hw.x, w1 = (float)hw.y;
                const half4 v = pl[ctr + dx*LCP + dy];
                const float4v f = {(float)v[0], (float)v[1], (float)v[2], (float)v[3]};
                sAv += WSPC[t] * f;
                b0a += w0 * f;
                b1a += w1 * f;
            }
        }
        {   // tap 48
            const uint2 wp = wbP[24 * 128 + px];
            half2f hw; __builtin_memcpy(&hw, &wp.x, 4);
            const float w0 = (float)hw.x, w1 = (float)hw.y;
            const half4 v = pl[ctr + SPAN*LCP + SPAN];
            const float4v f = {(float)v[0], (float)v[1], (float)v[2], (float)v[3]};
            sAv += WSPC[48] * f;
            b0a += w0 * f;
            b1a += w1 * f;
        }

        float q0v[4], q1v[4];
        if (isdiag) {
            #pragma unroll
            for (int i = 0; i < 4; ++i) {
                const float sAn = sAv[i] * snI;
                const float b0n = b0a[i] * bnI0;
                const float b1x = b1a[i] * bnI1;
                q0v[i] = uv0[i] - dsv[i]*sAn - dbv[i]*b0n;
                q1v[i] = uv1[i] - (dsv[i] + dbv[i]) + dsv[i]*sAn + dbv[i]*b1x;
            }
        } else {
            __syncthreads();   // smH dead -> region A becomes accF
            #pragma unroll
            for (int i = 0; i < 4; ++i) {
                accF[(4*g + i) * NPXT + px]      = sAv[i] * snI;
                accF[(20 + 4*g + i) * NPXT + px] = b0a[i] * bnI0;
                accF[(40 + 4*g + i) * NPXT + px] = b1a[i] * bnI1;
            }
            __syncthreads();
            float t1[4] = {0,0,0,0}, t2[4] = {0,0,0,0}, t3[4] = {0,0,0,0};
            #pragma unroll
            for (int cc = 0; cc < 20; ++cc) {
                const float sv  = accF[cc * NPXT + px];
                const float b0v = accF[(20 + cc) * NPXT + px];
                const float b1v = accF[(40 + cc) * NPXT + px];
                #pragma unroll
                for (int i = 0; i < 4; ++i) {
                    const float* mk = Msh + (ku + i) * 48;
                    t1[i] += mk[cc] * sv;
                    t2[i] += mk[20 + cc] * b0v;
                    t3[i] += mk[20 + cc] * b1v;
                }
            }
            #pragma unroll
            for (int i = 0; i < 4; ++i) {
                const float rs = Msh[(ku + i) * 48 + 40];
                q0v[i] = uv0[i] - t1[i] - t2[i];
                q1v[i] = uv1[i] - rs + t1[i] + t3[i];
            }
        }

        if (it == 4) {
            #pragma unroll
            for (int i = 0; i < 4; ++i) {
                const int ch = 4*g + i;
                if (ch < NC) {
                    out[(size_t)gp * NC + ch]          = q0v[i];
                    out[((size_t)NPIX + gp) * NC + ch] = q1v[i];
                }
            }
        } else {
            #pragma unroll
            for (int i = 0; i < 4; ++i) sh[i] = (_Float16)smx0(q0v[i], q1v[i]);
        }
    }
}

extern "C" void kernel_launch(void* const* d_in, const int* in_sizes, int n_in,
                              void* d_out, int out_size, void* d_ws, size_t ws_size,
                              hipStream_t stream) {
    const float* u      = (const float*)d_in[0];
    const float* rgb    = (const float*)d_in[1];
    const float* sw     = (const float*)d_in[2];
    const float* bw     = (const float*)d_in[3];
    const float* compat = (const float*)d_in[4];
    float* out = (float*)d_out;

    unsigned long long* gsmA = (unsigned long long*)d_ws;              // 1,024,000 B
    unsigned long long* gsmB = (unsigned long long*)((char*)d_ws + 1024000);
    unsigned* bar = (unsigned*)((char*)d_ws + 2048000);                // magic + epochs

    crf_kernel<<<dim3(WW/TC, HH/TR, 1), dim3(NTHR), 0, stream>>>(
        u, rgb, sw, bw, compat, gsmA, gsmB, bar, out);
}